// Round 12
// baseline (198.328 us; speedup 1.0000x reference)
//
#include <hip/hip_runtime.h>
#include <hip/hip_bf16.h>
#include <math.h>

#define N_NODES 10000
#define N_EDGES 640000
#define N_GRAPHS 64
#define DIM 128
#define NEG_SLOPE 0.01f
#define NB_CSR 128            // histogram partitions (5000 edges each)
#define EDGES_PER_BLK (N_EDGES / NB_CSR)

// ---------------- workspace layout (bytes) ----------------
// (fp32 feat slot at 0 unused; layout kept stable)
// resid    : 10,240,000 .. 20,480,000   float[2][10000][128]
// a_self   : 20,480,000                 float[2][10000]
// a_nb     : 20,560,000                 float[2][10000]
// deg      : 20,640,000                 int[10000]
// rowptr   : 20,688,000                 int[10001]
// csr_src  : 20,784,000                 int[640000]
// feat_b16 : 23,344,000 .. 28,464,000   bf16[2][10000][128]
// bh       : 28,464,000 .. 33,584,000   int[128][10000]
//
// LEDGER (measured A/B facts, rounds 0-11):
//  - fork-join side stream: +26us (R9 pure launcher A/B). Single stream only.
//  - LDS-staged node_scan: +32.5us (R6-R7). Keep dependent-chain version.
//  - MFMA gemm + LDS-transpose epilogue + fused attn scalars: -7.5us (R8).
//  - global returning atomics for CSR: +60us (R1). Keep LDS-cursor scatter.
//  - pool fusion into aggregate via phis atomics: +65us (R5). Keep separate.
//  - 4-deep feat-gather pipeline in aggregate: null (R10).
//  - b-merged aggregate: null/+2.6 (R11). Aggregate is gather-BW-bound
//    (~327MB random L2/L3 traffic, feat_b16 > 4MB per-XCD L2); ~40us floor.

__device__ __forceinline__ unsigned short f2bf(float f) {
    __hip_bfloat16 h = __float2bfloat16(f);
    return *reinterpret_cast<unsigned short*>(&h);
}

typedef __attribute__((ext_vector_type(8))) short short8v;  // 8 bf16 in 4 VGPR
typedef __attribute__((ext_vector_type(4))) float f32x4;

// ---------------- CSR build: phase 1, per-partition LDS histogram ----------------
__global__ __launch_bounds__(512) void csr_hist(const int4* __restrict__ edst4,
                                                int* __restrict__ bh) {
    __shared__ int hist[N_NODES];
    const int blk = blockIdx.x;
    const int t = threadIdx.x;
    for (int n = t; n < N_NODES; n += 512) hist[n] = 0;
    __syncthreads();
    const int base4 = blk * (EDGES_PER_BLK / 4);
    for (int i = t; i < EDGES_PER_BLK / 4; i += 512) {
        int4 d = edst4[base4 + i];
        atomicAdd(&hist[d.x], 1);
        atomicAdd(&hist[d.y], 1);
        atomicAdd(&hist[d.z], 1);
        atomicAdd(&hist[d.w], 1);
    }
    __syncthreads();
    int* dst = bh + (size_t)blk * N_NODES;
    for (int n = t; n < N_NODES; n += 512) dst[n] = hist[n];
}

// ---------------- CSR build: phase 2, per-node scan over partitions ----------------
// Constant-stride offsets -> LLVM proves independence, pipelines the loads.
// (LDS-staged variant measured +32.5us worse, R6-R7.)
__global__ __launch_bounds__(256) void csr_node_scan(int* __restrict__ bh,
                                                     int* __restrict__ deg) {
    int n = blockIdx.x * 256 + threadIdx.x;
    if (n >= N_NODES) return;
    int running = 0;
    for (int blk = 0; blk < NB_CSR; ++blk) {
        int* p = bh + (size_t)blk * N_NODES + n;
        int v = *p;
        *p = running;
        running += v;
    }
    deg[n] = running;
}

// ---------------- CSR build: phase 3, scatter (rowptr scan fused in prologue) ---
// R12 change: scan_deg dispatch deleted. Every block redundantly computes the
// exclusive scan of deg (512-thread strips + Hillis-Steele over partials,
// ~40KB L2-hot) -> cur[]; block 0 publishes rowptr for aggregate. Removes one
// dispatch AND its 1-block fully-serial machine-idle window.
__global__ __launch_bounds__(512) void csr_scatter(
    const int4* __restrict__ esrc4, const int4* __restrict__ edst4,
    const int* __restrict__ deg, const int* __restrict__ bh,
    int* __restrict__ rowptr, int* __restrict__ csr_src) {
    __shared__ int cur[N_NODES];        // 40,000 B
    __shared__ int psum[512];
    const int blk = blockIdx.x;
    const int t = threadIdx.x;

    // strip sums: thread t owns nodes [t*20, t*20+20)
    const int base = t * 20;
    int cnt = N_NODES - base;
    if (cnt < 0) cnt = 0;
    if (cnt > 20) cnt = 20;
    int s = 0;
    for (int i = 0; i < cnt; ++i) s += deg[base + i];
    psum[t] = s;
    __syncthreads();
    for (int off = 1; off < 512; off <<= 1) {
        int v = 0;
        if (t >= off) v = psum[t - off];
        __syncthreads();
        if (t >= off) psum[t] += v;
        __syncthreads();
    }
    int run = (t == 0) ? 0 : psum[t - 1];   // exclusive prefix of strip
    for (int i = 0; i < cnt; ++i) {
        cur[base + i] = run;
        if (blk == 0) rowptr[base + i] = run;
        run += deg[base + i];
    }
    if (blk == 0 && t == 0) rowptr[N_NODES] = psum[511];
    __syncthreads();

    // add per-partition offsets (coalesced)
    const int* boff = bh + (size_t)blk * N_NODES;
    for (int n = t; n < N_NODES; n += 512) cur[n] += boff[n];
    __syncthreads();

    const int base4 = blk * (EDGES_PER_BLK / 4);
    for (int i = t; i < EDGES_PER_BLK / 4; i += 512) {
        int4 sv = esrc4[base4 + i];
        int4 d = edst4[base4 + i];
        csr_src[atomicAdd(&cur[d.x], 1)] = sv.x;
        csr_src[atomicAdd(&cur[d.y], 1)] = sv.y;
        csr_src[atomicAdd(&cur[d.z], 1)] = sv.z;
        csr_src[atomicAdd(&cur[d.w], 1)] = sv.w;
    }
}

// ---------------- MFMA GEMM + fused attention scalars (verified R4/R8) ---------
#define LDK 136   // padded staging row (bf16): 272B stride, bank-balanced b128
struct GemmSmem {
    union {
        struct {
            unsigned short xs[64 * LDK];     // 17,408 B
            unsigned short wsh[128 * LDK];   // 34,816 B
        } in;
        float ot[64 * 132];                  // 33,792 B out-transpose tile
    };
};

__global__ __launch_bounds__(256) void gemm_mfma(
    const float* __restrict__ x, const float* __restrict__ Wfc,
    const float* __restrict__ bfc, const float* __restrict__ Wres,
    float* __restrict__ resid, unsigned short* __restrict__ feat_b16,
    const float* __restrict__ wl, const float* __restrict__ wr,
    float* __restrict__ a_self, float* __restrict__ a_nb) {
    __shared__ GemmSmem sm;
    const int which = blockIdx.y & 1;
    const int b = blockIdx.y >> 1;
    const float* __restrict__ W = (which ? Wres : Wfc) + (size_t)b * DIM * DIM;
    const int n0 = blockIdx.x * 64;
    const int t = threadIdx.x;

    {   // stage x: 64 rows; thread t -> row t>>2, k-quarter (t&3)*32
        const int r = t >> 2;
        const int kq = (t & 3) * 32;
        const int n = n0 + r;
        unsigned short tmp[32];
        if (n < N_NODES) {
            const float4* px = reinterpret_cast<const float4*>(x + (size_t)n * DIM + kq);
#pragma unroll
            for (int i = 0; i < 8; ++i) {
                float4 v = px[i];
                tmp[4 * i]     = f2bf(v.x);
                tmp[4 * i + 1] = f2bf(v.y);
                tmp[4 * i + 2] = f2bf(v.z);
                tmp[4 * i + 3] = f2bf(v.w);
            }
        } else {
#pragma unroll
            for (int i = 0; i < 32; ++i) tmp[i] = 0;
        }
#pragma unroll
        for (int i = 0; i < 4; ++i)
            *reinterpret_cast<short8v*>(&sm.in.xs[r * LDK + kq + 8 * i]) =
                *reinterpret_cast<const short8v*>(&tmp[8 * i]);
    }
    {   // stage W: 128 rows; thread t -> row t>>1, k-half (t&1)*64
        const int r = t >> 1;
        const int kh = (t & 1) * 64;
        const float4* pw = reinterpret_cast<const float4*>(W + (size_t)r * DIM + kh);
        unsigned short tmp[64];
#pragma unroll
        for (int i = 0; i < 16; ++i) {
            float4 v = pw[i];
            tmp[4 * i]     = f2bf(v.x);
            tmp[4 * i + 1] = f2bf(v.y);
            tmp[4 * i + 2] = f2bf(v.z);
            tmp[4 * i + 3] = f2bf(v.w);
        }
#pragma unroll
        for (int i = 0; i < 8; ++i)
            *reinterpret_cast<short8v*>(&sm.in.wsh[r * LDK + kh + 8 * i]) =
                *reinterpret_cast<const short8v*>(&tmp[8 * i]);
    }
    __syncthreads();

    const int wave = t >> 6;
    const int lane = t & 63;
    const int l16 = lane & 15;
    const int l4 = lane >> 4;

    f32x4 acc[8];
#pragma unroll
    for (int nf = 0; nf < 8; ++nf) acc[nf] = (f32x4){0.f, 0.f, 0.f, 0.f};

    const int arow = wave * 16 + l16;
#pragma unroll
    for (int ks = 0; ks < 4; ++ks) {
        short8v af = *reinterpret_cast<const short8v*>(
            &sm.in.xs[arow * LDK + ks * 32 + l4 * 8]);
#pragma unroll
        for (int nf = 0; nf < 8; ++nf) {
            short8v bfr = *reinterpret_cast<const short8v*>(
                &sm.in.wsh[(nf * 16 + l16) * LDK + ks * 32 + l4 * 8]);
            acc[nf] = __builtin_amdgcn_mfma_f32_16x16x32_bf16(af, bfr, acc[nf], 0, 0, 0);
        }
    }

    __syncthreads();   // all MFMA LDS reads done; reuse LDS as fp32 out-tile
    const int lrow = wave * 16 + l4 * 4;   // local row base of this lane's 4 rows

    if (which == 0) {
        float wlv[8], wrv[8], bv[8];
#pragma unroll
        for (int nf = 0; nf < 8; ++nf) {
            wlv[nf] = wl[b * DIM + nf * 16 + l16];
            wrv[nf] = wr[b * DIM + nf * 16 + l16];
            bv[nf]  = bfc[b * DIM + nf * 16 + l16];
        }
#pragma unroll
        for (int r = 0; r < 4; ++r) {
            float ps = 0.f, pr = 0.f;
#pragma unroll
            for (int nf = 0; nf < 8; ++nf) {
                float f = acc[nf][r] + bv[nf];
                sm.ot[(lrow + r) * 132 + nf * 16 + l16] = f;
                ps += f * wlv[nf];
                pr += f * wrv[nf];
            }
            // reduce across the 16 cols-per-lane-group (l16 bits 0..3)
#pragma unroll
            for (int off = 1; off < 16; off <<= 1) {
                ps += __shfl_xor(ps, off, 64);
                pr += __shfl_xor(pr, off, 64);
            }
            int n = n0 + lrow + r;
            if (l16 == 0 && n < N_NODES) {
                a_self[b * N_NODES + n] = ps;
                a_nb[b * N_NODES + n] = pr;
            }
        }
    } else {
#pragma unroll
        for (int r = 0; r < 4; ++r)
#pragma unroll
            for (int nf = 0; nf < 8; ++nf)
                sm.ot[(lrow + r) * 132 + nf * 16 + l16] = acc[nf][r];
    }
    __syncthreads();

    // coalesced writeback: thread t -> row t>>2, col-quarter (t&3)*32
    const int rr = t >> 2;
    const int cq = (t & 3) * 32;
    const int n = n0 + rr;
    if (n < N_NODES) {
        if (which == 0) {
            unsigned short tmp[32];
#pragma unroll
            for (int i = 0; i < 8; ++i) {
                float4 v = *reinterpret_cast<const float4*>(&sm.ot[rr * 132 + cq + 4 * i]);
                tmp[4 * i]     = f2bf(v.x);
                tmp[4 * i + 1] = f2bf(v.y);
                tmp[4 * i + 2] = f2bf(v.z);
                tmp[4 * i + 3] = f2bf(v.w);
            }
            unsigned short* dst = feat_b16 + ((size_t)b * N_NODES + n) * DIM + cq;
#pragma unroll
            for (int i = 0; i < 4; ++i)
                *reinterpret_cast<short8v*>(dst + 8 * i) =
                    *reinterpret_cast<const short8v*>(&tmp[8 * i]);
        } else {
            float* dst = resid + ((size_t)b * N_NODES + n) * DIM + cq;
#pragma unroll
            for (int i = 0; i < 8; ++i)
                *reinterpret_cast<float4*>(dst + 4 * i) =
                    *reinterpret_cast<const float4*>(&sm.ot[rr * 132 + cq + 4 * i]);
        }
    }
}

// ---------------- softmax + weighted aggregation + residual + relu ----------------
// R10 version (best measured, 159.7): 4-deep pipelined feat gather.
__device__ __forceinline__ void fma8(float acc[8], uint4 f, float w) {
#pragma unroll
    for (int k = 0; k < 4; ++k) {
        unsigned int u = (&f.x)[k];
        acc[2 * k]     += w * __uint_as_float(u << 16);
        acc[2 * k + 1] += w * __uint_as_float(u & 0xffff0000u);
    }
}

__global__ __launch_bounds__(256) void aggregate(
    const unsigned short* __restrict__ feat_b16, const float* __restrict__ resid,
    const float* __restrict__ a_self, const float* __restrict__ a_nb,
    const int* __restrict__ rowptr, const int* __restrict__ csr_src,
    float* __restrict__ out) {
    const int wave = threadIdx.x >> 6;
    const int lane = threadIdx.x & 63;
    const int n = blockIdx.x * 4 + wave;
    const int b = blockIdx.y;
    const int q = lane >> 4;     // edge slot within group of 4
    const int l16 = lane & 15;   // covers channels [l16*8, l16*8+8)
    const int start = rowptr[n];
    const int end = rowptr[n + 1];

    const float* __restrict__ anb = a_nb + b * N_NODES;
    const uint4* __restrict__ fb =
        reinterpret_cast<const uint4*>(feat_b16 + (size_t)b * N_NODES * DIM);
    const float asl = a_self[b * N_NODES + n];

    float acc[8];
#pragma unroll
    for (int k = 0; k < 8; ++k) acc[k] = 0.f;
    float dpart = 0.f;

    for (int c = start; c < end; c += 64) {
        int j = c + lane;
        float e = 0.f;
        int src = 0;
        if (j < end) {
            src = csr_src[j];
            float s = asl + anb[src];
            s = (s >= 0.f) ? s : NEG_SLOPE * s;
            e = __expf(s);
        }
        dpart += e;
        int cnt = end - c;
        if (cnt > 64) cnt = 64;
        const int iters = (cnt + 3) >> 2;    // groups of 4 edges, 1..16
        const int m4 = (iters + 3) >> 2;     // macro steps of 4 groups

#define GLOAD(F, W, IDX) { int _i = (IDX); W = __shfl(e, _i, 64);             \
        int _s = __shfl(src, _i, 64); F = fb[(size_t)_s * 16 + l16]; }

        float w0, w1, w2, w3;
        uint4 f0, f1, f2, f3;
        GLOAD(f0, w0, 0 + q);
        GLOAD(f1, w1, 4 + q);
        GLOAD(f2, w2, 8 + q);
        GLOAD(f3, w3, 12 + q);

        for (int m = 0; m < m4; ++m) {
            const bool more = (m + 1 < m4);          // wave-uniform
            const int nb16 = 16 * (m + 1);           // next macro-step lane base
            fma8(acc, f0, w0);
            if (more) GLOAD(f0, w0, nb16 + q);
            fma8(acc, f1, w1);
            if (more) GLOAD(f1, w1, nb16 + 4 + q);
            fma8(acc, f2, w2);
            if (more) GLOAD(f2, w2, nb16 + 8 + q);
            fma8(acc, f3, w3);
            if (more) GLOAD(f3, w3, nb16 + 12 + q);
        }
#undef GLOAD
    }

#pragma unroll
    for (int k = 0; k < 8; ++k) {
        acc[k] += __shfl_xor(acc[k], 16, 64);
        acc[k] += __shfl_xor(acc[k], 32, 64);
    }
    float denom = dpart;
#pragma unroll
    for (int off = 32; off > 0; off >>= 1) denom += __shfl_xor(denom, off, 64);

    if (q == 0) {
        float inv = (end > start) ? 1.f / denom : 0.f;
        const float4* rr = reinterpret_cast<const float4*>(
            resid + ((size_t)b * N_NODES + n) * DIM);
        float4 r0 = rr[l16 * 2];
        float4 r1 = rr[l16 * 2 + 1];
        float4 o0, o1;
        o0.x = fmaxf(acc[0] * inv + r0.x, 0.f);
        o0.y = fmaxf(acc[1] * inv + r0.y, 0.f);
        o0.z = fmaxf(acc[2] * inv + r0.z, 0.f);
        o0.w = fmaxf(acc[3] * inv + r0.w, 0.f);
        o1.x = fmaxf(acc[4] * inv + r1.x, 0.f);
        o1.y = fmaxf(acc[5] * inv + r1.y, 0.f);
        o1.z = fmaxf(acc[6] * inv + r1.z, 0.f);
        o1.w = fmaxf(acc[7] * inv + r1.w, 0.f);
        float4* po = reinterpret_cast<float4*>(out + (size_t)n * (2 * DIM) + b * DIM);
        po[l16 * 2] = o0;
        po[l16 * 2 + 1] = o1;
    }
}

// ---------------- per-graph sum pooling (atomic-free, no memset needed) --------
// R12 change: gids sorted -> each graph's rows are a contiguous span of `out`.
// One block per graph, thread = channel, direct accumulate + direct store.
__device__ int lower_bound_dev(const int* __restrict__ a, int n, int key) {
    int lo = 0, hi = n;
    while (lo < hi) {
        int mid = (lo + hi) >> 1;
        if (a[mid] < key) lo = mid + 1;
        else hi = mid;
    }
    return lo;
}

__global__ __launch_bounds__(256) void pool_graphs(
    const float* __restrict__ h, const int* __restrict__ gids,
    float* __restrict__ phis) {
    const int g = blockIdx.x;
    const int tid = threadIdx.x;
    int lo = lower_bound_dev(gids, N_NODES, g);
    int hi = lower_bound_dev(gids, N_NODES, g + 1);
    float acc = 0.f;
    for (int n = lo; n < hi; ++n) acc += h[(size_t)n * (2 * DIM) + tid];
    phis[(size_t)g * (2 * DIM) + tid] = acc;
}

extern "C" void kernel_launch(void* const* d_in, const int* in_sizes, int n_in,
                              void* d_out, int out_size, void* d_ws, size_t ws_size,
                              hipStream_t stream) {
    const float* x    = (const float*)d_in[0];
    const int* esrc   = (const int*)d_in[1];
    const int* edst   = (const int*)d_in[2];
    const int* gids   = (const int*)d_in[3];
    const float* Wfc  = (const float*)d_in[4];
    const float* bfc  = (const float*)d_in[5];
    const float* wl   = (const float*)d_in[6];
    const float* wr   = (const float*)d_in[7];
    const float* Wres = (const float*)d_in[8];
    float* out = (float*)d_out;

    char* ws = (char*)d_ws;
    float* resid   = (float*)(ws + 10240000);
    float* a_self  = (float*)(ws + 20480000);
    float* a_nb    = (float*)(ws + 20560000);
    int*   deg     = (int*)(ws + 20640000);
    int*   rowptr  = (int*)(ws + 20688000);
    int*   csr_src = (int*)(ws + 20784000);
    unsigned short* feat_b16 = (unsigned short*)(ws + 23344000);
    int*   bh      = (int*)(ws + 28464000);

    float* phis = out + (size_t)N_NODES * 2 * DIM;

    // 6 dispatches, no memsets: a_self/a_nb/rowptr/phis all stored directly.
    csr_hist<<<NB_CSR, 512, 0, stream>>>((const int4*)edst, bh);
    csr_node_scan<<<(N_NODES + 255) / 256, 256, 0, stream>>>(bh, deg);
    csr_scatter<<<NB_CSR, 512, 0, stream>>>(
        (const int4*)esrc, (const int4*)edst, deg, bh, rowptr, csr_src);

    gemm_mfma<<<dim3((N_NODES + 63) / 64, 4), 256, 0, stream>>>(
        x, Wfc, bfc, Wres, resid, feat_b16, wl, wr, a_self, a_nb);

    aggregate<<<dim3(2500, 2), 256, 0, stream>>>(
        feat_b16, resid, a_self, a_nb, rowptr, csr_src, out);
    pool_graphs<<<N_GRAPHS, 256, 0, stream>>>(out, gids, phis);
}

// Round 13
// 161.055 us; speedup vs baseline: 1.2314x; 1.2314x over previous
//
#include <hip/hip_runtime.h>
#include <hip/hip_bf16.h>
#include <math.h>

#define N_NODES 10000
#define N_EDGES 640000
#define N_GRAPHS 64
#define DIM 128
#define NEG_SLOPE 0.01f
#define NB_CSR 128            // histogram partitions (5000 edges each)
#define EDGES_PER_BLK (N_EDGES / NB_CSR)

// ---------------- workspace layout (bytes) ----------------
// (fp32 feat slot at 0 unused; layout kept stable)
// resid    : 10,240,000 .. 20,480,000   float[2][10000][128]
// a_self   : 20,480,000                 float[2][10000]
// a_nb     : 20,560,000                 float[2][10000]
// deg      : 20,640,000                 int[10000]
// rowptr   : 20,688,000                 int[10001]
// csr_src  : 20,784,000                 int[640000]
// feat_b16 : 23,344,000 .. 28,464,000   bf16[2][10000][128]
// bh       : 28,464,000 .. 33,584,000   int[128][10000]
//
// LEDGER (measured A/B facts, rounds 0-12):
//  - fork-join side stream: +26us (R9 pure launcher A/B). Single stream only.
//  - LDS-staged node_scan: +32.5us (R6-R7). Keep dependent-chain version.
//  - MFMA gemm + LDS-transpose epilogue + fused attn scalars: -7.5us (R8).
//  - global returning atomics for CSR: +60us (R1). Keep LDS-cursor scatter.
//  - pool fusion into aggregate via phis atomics: +65us (R5). Keep separate.
//  - 4-deep feat-gather pipeline in aggregate: null (R10).
//  - b-merged aggregate: null (R11). Aggregate is gather-BW-bound; ~40us floor.
//  - scan_deg fused into scatter prologue: ~-5us (R12, masked). Keep.
//  - 64-block chunkless pool: +43us (R12, measured 48us direct). Tiny grids
//    are latency death; keep 1024-block chunked pool with bounded atomics.

__device__ __forceinline__ unsigned short f2bf(float f) {
    __hip_bfloat16 h = __float2bfloat16(f);
    return *reinterpret_cast<unsigned short*>(&h);
}

typedef __attribute__((ext_vector_type(8))) short short8v;  // 8 bf16 in 4 VGPR
typedef __attribute__((ext_vector_type(4))) float f32x4;

// ---------------- CSR build: phase 1, per-partition LDS histogram ----------------
__global__ __launch_bounds__(512) void csr_hist(const int4* __restrict__ edst4,
                                                int* __restrict__ bh) {
    __shared__ int hist[N_NODES];
    const int blk = blockIdx.x;
    const int t = threadIdx.x;
    for (int n = t; n < N_NODES; n += 512) hist[n] = 0;
    __syncthreads();
    const int base4 = blk * (EDGES_PER_BLK / 4);
    for (int i = t; i < EDGES_PER_BLK / 4; i += 512) {
        int4 d = edst4[base4 + i];
        atomicAdd(&hist[d.x], 1);
        atomicAdd(&hist[d.y], 1);
        atomicAdd(&hist[d.z], 1);
        atomicAdd(&hist[d.w], 1);
    }
    __syncthreads();
    int* dst = bh + (size_t)blk * N_NODES;
    for (int n = t; n < N_NODES; n += 512) dst[n] = hist[n];
}

// ---------------- CSR build: phase 2, per-node scan over partitions ----------------
// Constant-stride offsets -> LLVM proves independence, pipelines the loads.
// (LDS-staged variant measured +32.5us worse, R6-R7.)
__global__ __launch_bounds__(256) void csr_node_scan(int* __restrict__ bh,
                                                     int* __restrict__ deg) {
    int n = blockIdx.x * 256 + threadIdx.x;
    if (n >= N_NODES) return;
    int running = 0;
    for (int blk = 0; blk < NB_CSR; ++blk) {
        int* p = bh + (size_t)blk * N_NODES + n;
        int v = *p;
        *p = running;
        running += v;
    }
    deg[n] = running;
}

// ---------------- CSR build: phase 3, scatter (rowptr scan fused in prologue) ---
// scan_deg dispatch deleted (R12, ~-5us): every block redundantly computes the
// exclusive scan of deg (512-thread strips + Hillis-Steele over partials,
// ~40KB L2-hot) -> cur[]; block 0 publishes rowptr for aggregate.
__global__ __launch_bounds__(512) void csr_scatter(
    const int4* __restrict__ esrc4, const int4* __restrict__ edst4,
    const int* __restrict__ deg, const int* __restrict__ bh,
    int* __restrict__ rowptr, int* __restrict__ csr_src) {
    __shared__ int cur[N_NODES];        // 40,000 B
    __shared__ int psum[512];
    const int blk = blockIdx.x;
    const int t = threadIdx.x;

    // strip sums: thread t owns nodes [t*20, t*20+20)
    const int base = t * 20;
    int cnt = N_NODES - base;
    if (cnt < 0) cnt = 0;
    if (cnt > 20) cnt = 20;
    int s = 0;
    for (int i = 0; i < cnt; ++i) s += deg[base + i];
    psum[t] = s;
    __syncthreads();
    for (int off = 1; off < 512; off <<= 1) {
        int v = 0;
        if (t >= off) v = psum[t - off];
        __syncthreads();
        if (t >= off) psum[t] += v;
        __syncthreads();
    }
    int run = (t == 0) ? 0 : psum[t - 1];   // exclusive prefix of strip
    for (int i = 0; i < cnt; ++i) {
        cur[base + i] = run;
        if (blk == 0) rowptr[base + i] = run;
        run += deg[base + i];
    }
    if (blk == 0 && t == 0) rowptr[N_NODES] = psum[511];
    __syncthreads();

    // add per-partition offsets (coalesced)
    const int* boff = bh + (size_t)blk * N_NODES;
    for (int n = t; n < N_NODES; n += 512) cur[n] += boff[n];
    __syncthreads();

    const int base4 = blk * (EDGES_PER_BLK / 4);
    for (int i = t; i < EDGES_PER_BLK / 4; i += 512) {
        int4 sv = esrc4[base4 + i];
        int4 d = edst4[base4 + i];
        csr_src[atomicAdd(&cur[d.x], 1)] = sv.x;
        csr_src[atomicAdd(&cur[d.y], 1)] = sv.y;
        csr_src[atomicAdd(&cur[d.z], 1)] = sv.z;
        csr_src[atomicAdd(&cur[d.w], 1)] = sv.w;
    }
}

// ---------------- MFMA GEMM + fused attention scalars (verified R4/R8) ---------
#define LDK 136   // padded staging row (bf16): 272B stride, bank-balanced b128
struct GemmSmem {
    union {
        struct {
            unsigned short xs[64 * LDK];     // 17,408 B
            unsigned short wsh[128 * LDK];   // 34,816 B
        } in;
        float ot[64 * 132];                  // 33,792 B out-transpose tile
    };
};

__global__ __launch_bounds__(256) void gemm_mfma(
    const float* __restrict__ x, const float* __restrict__ Wfc,
    const float* __restrict__ bfc, const float* __restrict__ Wres,
    float* __restrict__ resid, unsigned short* __restrict__ feat_b16,
    const float* __restrict__ wl, const float* __restrict__ wr,
    float* __restrict__ a_self, float* __restrict__ a_nb) {
    __shared__ GemmSmem sm;
    const int which = blockIdx.y & 1;
    const int b = blockIdx.y >> 1;
    const float* __restrict__ W = (which ? Wres : Wfc) + (size_t)b * DIM * DIM;
    const int n0 = blockIdx.x * 64;
    const int t = threadIdx.x;

    {   // stage x: 64 rows; thread t -> row t>>2, k-quarter (t&3)*32
        const int r = t >> 2;
        const int kq = (t & 3) * 32;
        const int n = n0 + r;
        unsigned short tmp[32];
        if (n < N_NODES) {
            const float4* px = reinterpret_cast<const float4*>(x + (size_t)n * DIM + kq);
#pragma unroll
            for (int i = 0; i < 8; ++i) {
                float4 v = px[i];
                tmp[4 * i]     = f2bf(v.x);
                tmp[4 * i + 1] = f2bf(v.y);
                tmp[4 * i + 2] = f2bf(v.z);
                tmp[4 * i + 3] = f2bf(v.w);
            }
        } else {
#pragma unroll
            for (int i = 0; i < 32; ++i) tmp[i] = 0;
        }
#pragma unroll
        for (int i = 0; i < 4; ++i)
            *reinterpret_cast<short8v*>(&sm.in.xs[r * LDK + kq + 8 * i]) =
                *reinterpret_cast<const short8v*>(&tmp[8 * i]);
    }
    {   // stage W: 128 rows; thread t -> row t>>1, k-half (t&1)*64
        const int r = t >> 1;
        const int kh = (t & 1) * 64;
        const float4* pw = reinterpret_cast<const float4*>(W + (size_t)r * DIM + kh);
        unsigned short tmp[64];
#pragma unroll
        for (int i = 0; i < 16; ++i) {
            float4 v = pw[i];
            tmp[4 * i]     = f2bf(v.x);
            tmp[4 * i + 1] = f2bf(v.y);
            tmp[4 * i + 2] = f2bf(v.z);
            tmp[4 * i + 3] = f2bf(v.w);
        }
#pragma unroll
        for (int i = 0; i < 8; ++i)
            *reinterpret_cast<short8v*>(&sm.in.wsh[r * LDK + kh + 8 * i]) =
                *reinterpret_cast<const short8v*>(&tmp[8 * i]);
    }
    __syncthreads();

    const int wave = t >> 6;
    const int lane = t & 63;
    const int l16 = lane & 15;
    const int l4 = lane >> 4;

    f32x4 acc[8];
#pragma unroll
    for (int nf = 0; nf < 8; ++nf) acc[nf] = (f32x4){0.f, 0.f, 0.f, 0.f};

    const int arow = wave * 16 + l16;
#pragma unroll
    for (int ks = 0; ks < 4; ++ks) {
        short8v af = *reinterpret_cast<const short8v*>(
            &sm.in.xs[arow * LDK + ks * 32 + l4 * 8]);
#pragma unroll
        for (int nf = 0; nf < 8; ++nf) {
            short8v bfr = *reinterpret_cast<const short8v*>(
                &sm.in.wsh[(nf * 16 + l16) * LDK + ks * 32 + l4 * 8]);
            acc[nf] = __builtin_amdgcn_mfma_f32_16x16x32_bf16(af, bfr, acc[nf], 0, 0, 0);
        }
    }

    __syncthreads();   // all MFMA LDS reads done; reuse LDS as fp32 out-tile
    const int lrow = wave * 16 + l4 * 4;   // local row base of this lane's 4 rows

    if (which == 0) {
        float wlv[8], wrv[8], bv[8];
#pragma unroll
        for (int nf = 0; nf < 8; ++nf) {
            wlv[nf] = wl[b * DIM + nf * 16 + l16];
            wrv[nf] = wr[b * DIM + nf * 16 + l16];
            bv[nf]  = bfc[b * DIM + nf * 16 + l16];
        }
#pragma unroll
        for (int r = 0; r < 4; ++r) {
            float ps = 0.f, pr = 0.f;
#pragma unroll
            for (int nf = 0; nf < 8; ++nf) {
                float f = acc[nf][r] + bv[nf];
                sm.ot[(lrow + r) * 132 + nf * 16 + l16] = f;
                ps += f * wlv[nf];
                pr += f * wrv[nf];
            }
            // reduce across the 16 cols-per-lane-group (l16 bits 0..3)
#pragma unroll
            for (int off = 1; off < 16; off <<= 1) {
                ps += __shfl_xor(ps, off, 64);
                pr += __shfl_xor(pr, off, 64);
            }
            int n = n0 + lrow + r;
            if (l16 == 0 && n < N_NODES) {
                a_self[b * N_NODES + n] = ps;
                a_nb[b * N_NODES + n] = pr;
            }
        }
    } else {
#pragma unroll
        for (int r = 0; r < 4; ++r)
#pragma unroll
            for (int nf = 0; nf < 8; ++nf)
                sm.ot[(lrow + r) * 132 + nf * 16 + l16] = acc[nf][r];
    }
    __syncthreads();

    // coalesced writeback: thread t -> row t>>2, col-quarter (t&3)*32
    const int rr = t >> 2;
    const int cq = (t & 3) * 32;
    const int n = n0 + rr;
    if (n < N_NODES) {
        if (which == 0) {
            unsigned short tmp[32];
#pragma unroll
            for (int i = 0; i < 8; ++i) {
                float4 v = *reinterpret_cast<const float4*>(&sm.ot[rr * 132 + cq + 4 * i]);
                tmp[4 * i]     = f2bf(v.x);
                tmp[4 * i + 1] = f2bf(v.y);
                tmp[4 * i + 2] = f2bf(v.z);
                tmp[4 * i + 3] = f2bf(v.w);
            }
            unsigned short* dst = feat_b16 + ((size_t)b * N_NODES + n) * DIM + cq;
#pragma unroll
            for (int i = 0; i < 4; ++i)
                *reinterpret_cast<short8v*>(dst + 8 * i) =
                    *reinterpret_cast<const short8v*>(&tmp[8 * i]);
        } else {
            float* dst = resid + ((size_t)b * N_NODES + n) * DIM + cq;
#pragma unroll
            for (int i = 0; i < 8; ++i)
                *reinterpret_cast<float4*>(dst + 4 * i) =
                    *reinterpret_cast<const float4*>(&sm.ot[rr * 132 + cq + 4 * i]);
        }
    }
}

// ---------------- softmax + weighted aggregation + residual + relu ----------------
// R10 version (best measured): 4-deep pipelined feat gather.
__device__ __forceinline__ void fma8(float acc[8], uint4 f, float w) {
#pragma unroll
    for (int k = 0; k < 4; ++k) {
        unsigned int u = (&f.x)[k];
        acc[2 * k]     += w * __uint_as_float(u << 16);
        acc[2 * k + 1] += w * __uint_as_float(u & 0xffff0000u);
    }
}

__global__ __launch_bounds__(256) void aggregate(
    const unsigned short* __restrict__ feat_b16, const float* __restrict__ resid,
    const float* __restrict__ a_self, const float* __restrict__ a_nb,
    const int* __restrict__ rowptr, const int* __restrict__ csr_src,
    float* __restrict__ out) {
    const int wave = threadIdx.x >> 6;
    const int lane = threadIdx.x & 63;
    const int n = blockIdx.x * 4 + wave;
    const int b = blockIdx.y;
    const int q = lane >> 4;     // edge slot within group of 4
    const int l16 = lane & 15;   // covers channels [l16*8, l16*8+8)
    const int start = rowptr[n];
    const int end = rowptr[n + 1];

    const float* __restrict__ anb = a_nb + b * N_NODES;
    const uint4* __restrict__ fb =
        reinterpret_cast<const uint4*>(feat_b16 + (size_t)b * N_NODES * DIM);
    const float asl = a_self[b * N_NODES + n];

    float acc[8];
#pragma unroll
    for (int k = 0; k < 8; ++k) acc[k] = 0.f;
    float dpart = 0.f;

    for (int c = start; c < end; c += 64) {
        int j = c + lane;
        float e = 0.f;
        int src = 0;
        if (j < end) {
            src = csr_src[j];
            float s = asl + anb[src];
            s = (s >= 0.f) ? s : NEG_SLOPE * s;
            e = __expf(s);
        }
        dpart += e;
        int cnt = end - c;
        if (cnt > 64) cnt = 64;
        const int iters = (cnt + 3) >> 2;    // groups of 4 edges, 1..16
        const int m4 = (iters + 3) >> 2;     // macro steps of 4 groups

#define GLOAD(F, W, IDX) { int _i = (IDX); W = __shfl(e, _i, 64);             \
        int _s = __shfl(src, _i, 64); F = fb[(size_t)_s * 16 + l16]; }

        float w0, w1, w2, w3;
        uint4 f0, f1, f2, f3;
        GLOAD(f0, w0, 0 + q);
        GLOAD(f1, w1, 4 + q);
        GLOAD(f2, w2, 8 + q);
        GLOAD(f3, w3, 12 + q);

        for (int m = 0; m < m4; ++m) {
            const bool more = (m + 1 < m4);          // wave-uniform
            const int nb16 = 16 * (m + 1);           // next macro-step lane base
            fma8(acc, f0, w0);
            if (more) GLOAD(f0, w0, nb16 + q);
            fma8(acc, f1, w1);
            if (more) GLOAD(f1, w1, nb16 + 4 + q);
            fma8(acc, f2, w2);
            if (more) GLOAD(f2, w2, nb16 + 8 + q);
            fma8(acc, f3, w3);
            if (more) GLOAD(f3, w3, nb16 + 12 + q);
        }
#undef GLOAD
    }

#pragma unroll
    for (int k = 0; k < 8; ++k) {
        acc[k] += __shfl_xor(acc[k], 16, 64);
        acc[k] += __shfl_xor(acc[k], 32, 64);
    }
    float denom = dpart;
#pragma unroll
    for (int off = 32; off > 0; off >>= 1) denom += __shfl_xor(denom, off, 64);

    if (q == 0) {
        float inv = (end > start) ? 1.f / denom : 0.f;
        const float4* rr = reinterpret_cast<const float4*>(
            resid + ((size_t)b * N_NODES + n) * DIM);
        float4 r0 = rr[l16 * 2];
        float4 r1 = rr[l16 * 2 + 1];
        float4 o0, o1;
        o0.x = fmaxf(acc[0] * inv + r0.x, 0.f);
        o0.y = fmaxf(acc[1] * inv + r0.y, 0.f);
        o0.z = fmaxf(acc[2] * inv + r0.z, 0.f);
        o0.w = fmaxf(acc[3] * inv + r0.w, 0.f);
        o1.x = fmaxf(acc[4] * inv + r1.x, 0.f);
        o1.y = fmaxf(acc[5] * inv + r1.y, 0.f);
        o1.z = fmaxf(acc[6] * inv + r1.z, 0.f);
        o1.w = fmaxf(acc[7] * inv + r1.w, 0.f);
        float4* po = reinterpret_cast<float4*>(out + (size_t)n * (2 * DIM) + b * DIM);
        po[l16 * 2] = o0;
        po[l16 * 2 + 1] = o1;
    }
}

// ---------------- per-graph sum pooling (chunked, 1024 blocks - anchor form) ---
// R12 lesson: the 64-block chunkless variant measured 48us (latency-bound tiny
// grid). This chunked form (grid 64x16, bounded atomics) never entered top-5.
__device__ int lower_bound_dev(const int* __restrict__ a, int n, int key) {
    int lo = 0, hi = n;
    while (lo < hi) {
        int mid = (lo + hi) >> 1;
        if (a[mid] < key) lo = mid + 1;
        else hi = mid;
    }
    return lo;
}

__global__ __launch_bounds__(256) void pool_graphs(
    const float* __restrict__ h, const int* __restrict__ gids,
    float* __restrict__ phis) {
    const int g = blockIdx.x;
    const int chunk = blockIdx.y;
    const int tid = threadIdx.x;
    int lo = lower_bound_dev(gids, N_NODES, g);
    int hi = lower_bound_dev(gids, N_NODES, g + 1);
    float acc = 0.f;
    for (int n = lo + chunk; n < hi; n += 16) acc += h[(size_t)n * (2 * DIM) + tid];
    if (acc != 0.f) atomicAdd(&phis[(size_t)g * (2 * DIM) + tid], acc);
}

extern "C" void kernel_launch(void* const* d_in, const int* in_sizes, int n_in,
                              void* d_out, int out_size, void* d_ws, size_t ws_size,
                              hipStream_t stream) {
    const float* x    = (const float*)d_in[0];
    const int* esrc   = (const int*)d_in[1];
    const int* edst   = (const int*)d_in[2];
    const int* gids   = (const int*)d_in[3];
    const float* Wfc  = (const float*)d_in[4];
    const float* bfc  = (const float*)d_in[5];
    const float* wl   = (const float*)d_in[6];
    const float* wr   = (const float*)d_in[7];
    const float* Wres = (const float*)d_in[8];
    float* out = (float*)d_out;

    char* ws = (char*)d_ws;
    float* resid   = (float*)(ws + 10240000);
    float* a_self  = (float*)(ws + 20480000);
    float* a_nb    = (float*)(ws + 20560000);
    int*   deg     = (int*)(ws + 20640000);
    int*   rowptr  = (int*)(ws + 20688000);
    int*   csr_src = (int*)(ws + 20784000);
    unsigned short* feat_b16 = (unsigned short*)(ws + 23344000);
    int*   bh      = (int*)(ws + 28464000);

    float* phis = out + (size_t)N_NODES * 2 * DIM;

    // phis accumulated via atomics -> zero it. a_self/a_nb/rowptr stored directly.
    hipMemsetAsync(phis, 0, N_GRAPHS * 2 * DIM * sizeof(float), stream);

    csr_hist<<<NB_CSR, 512, 0, stream>>>((const int4*)edst, bh);
    csr_node_scan<<<(N_NODES + 255) / 256, 256, 0, stream>>>(bh, deg);
    csr_scatter<<<NB_CSR, 512, 0, stream>>>(
        (const int4*)esrc, (const int4*)edst, deg, bh, rowptr, csr_src);

    gemm_mfma<<<dim3((N_NODES + 63) / 64, 4), 256, 0, stream>>>(
        x, Wfc, bfc, Wres, resid, feat_b16, wl, wr, a_self, a_nb);

    aggregate<<<dim3(2500, 2), 256, 0, stream>>>(
        feat_b16, resid, a_self, a_nb, rowptr, csr_src, out);
    pool_graphs<<<dim3(N_GRAPHS, 16), 256, 0, stream>>>(out, gids, phis);
}

// Round 14
// 157.509 us; speedup vs baseline: 1.2592x; 1.0225x over previous
//
#include <hip/hip_runtime.h>
#include <hip/hip_bf16.h>
#include <math.h>

#define N_NODES 10000
#define N_EDGES 640000
#define N_GRAPHS 64
#define DIM 128
#define NEG_SLOPE 0.01f
#define NB_CSR 128            // histogram partitions (5000 edges each)
#define EDGES_PER_BLK (N_EDGES / NB_CSR)

// ---------------- workspace layout (bytes) ----------------
// (fp32 feat slot at 0 unused; layout kept stable)
// resid    : 10,240,000 .. 20,480,000   float[2][10000][128]
// a_self   : 20,480,000                 float[2][10000]
// a_nb     : 20,560,000                 float[2][10000]
// deg      : 20,640,000                 int[10000]
// rowptr   : 20,688,000                 int[10001]
// csr_src  : 20,784,000                 int[640000]
// feat_b16 : 23,344,000 .. 28,464,000   bf16[2][10000][128]
// bh       : 28,464,000 .. 33,584,000   int[128][10000]
//
// LEDGER (measured A/B facts, rounds 0-13):
//  - fork-join side stream: +26us (R9 pure launcher A/B). Single stream only.
//  - LDS-staged node_scan: +32.5us (R6-R7). Keep dependent-chain version.
//  - MFMA gemm + LDS-transpose epilogue + fused attn scalars: -7.5us (R8).
//  - global returning atomics for CSR: +60us (R1). Keep LDS-cursor scatter.
//  - pool fusion into aggregate via phis atomics: +65us (R5). Keep separate.
//  - 4-deep feat-gather pipeline in aggregate: null (R10).
//  - b-merged aggregate: null (R11). Aggregate is gather-BW-bound; ~40us floor.
//  - scan_deg fused into scatter prologue: ~neutral (R12/R13). Keep (1 fewer dispatch).
//  - 64-block chunkless pool: +43us (R12). Tiny grids = latency death.
//  - R2 grid-z hist fusion: +30us — confounds: z dispatches LAST (serial tail)
//    + packed 16-bit counters (2x LDS-atomic contention). R14 retries with
//    flat-x-first ordering + 32-bit counters.

__device__ __forceinline__ unsigned short f2bf(float f) {
    __hip_bfloat16 h = __float2bfloat16(f);
    return *reinterpret_cast<unsigned short*>(&h);
}

typedef __attribute__((ext_vector_type(8))) short short8v;  // 8 bf16 in 4 VGPR
typedef __attribute__((ext_vector_type(4))) float f32x4;

// ---------------- CSR build: per-node scan over partitions ----------------
// Constant-stride offsets -> LLVM proves independence, pipelines the loads.
// (LDS-staged variant measured +32.5us worse, R6-R7.)
__global__ __launch_bounds__(256) void csr_node_scan(int* __restrict__ bh,
                                                     int* __restrict__ deg) {
    int n = blockIdx.x * 256 + threadIdx.x;
    if (n >= N_NODES) return;
    int running = 0;
    for (int blk = 0; blk < NB_CSR; ++blk) {
        int* p = bh + (size_t)blk * N_NODES + n;
        int v = *p;
        *p = running;
        running += v;
    }
    deg[n] = running;
}

// ---------------- CSR build: scatter (rowptr scan fused in prologue) ---
// scan_deg dispatch deleted (R12): every block redundantly computes the
// exclusive scan of deg (512-thread strips + Hillis-Steele over partials,
// ~40KB L2-hot) -> cur[]; block 0 publishes rowptr for aggregate.
__global__ __launch_bounds__(512) void csr_scatter(
    const int4* __restrict__ esrc4, const int4* __restrict__ edst4,
    const int* __restrict__ deg, const int* __restrict__ bh,
    int* __restrict__ rowptr, int* __restrict__ csr_src) {
    __shared__ int cur[N_NODES];        // 40,000 B
    __shared__ int psum[512];
    const int blk = blockIdx.x;
    const int t = threadIdx.x;

    // strip sums: thread t owns nodes [t*20, t*20+20)
    const int base = t * 20;
    int cnt = N_NODES - base;
    if (cnt < 0) cnt = 0;
    if (cnt > 20) cnt = 20;
    int s = 0;
    for (int i = 0; i < cnt; ++i) s += deg[base + i];
    psum[t] = s;
    __syncthreads();
    for (int off = 1; off < 512; off <<= 1) {
        int v = 0;
        if (t >= off) v = psum[t - off];
        __syncthreads();
        if (t >= off) psum[t] += v;
        __syncthreads();
    }
    int run = (t == 0) ? 0 : psum[t - 1];   // exclusive prefix of strip
    for (int i = 0; i < cnt; ++i) {
        cur[base + i] = run;
        if (blk == 0) rowptr[base + i] = run;
        run += deg[base + i];
    }
    if (blk == 0 && t == 0) rowptr[N_NODES] = psum[511];
    __syncthreads();

    // add per-partition offsets (coalesced)
    const int* boff = bh + (size_t)blk * N_NODES;
    for (int n = t; n < N_NODES; n += 512) cur[n] += boff[n];
    __syncthreads();

    const int base4 = blk * (EDGES_PER_BLK / 4);
    for (int i = t; i < EDGES_PER_BLK / 4; i += 512) {
        int4 sv = esrc4[base4 + i];
        int4 d = edst4[base4 + i];
        csr_src[atomicAdd(&cur[d.x], 1)] = sv.x;
        csr_src[atomicAdd(&cur[d.y], 1)] = sv.y;
        csr_src[atomicAdd(&cur[d.z], 1)] = sv.z;
        csr_src[atomicAdd(&cur[d.w], 1)] = sv.w;
    }
}

// ---------------- fused MFMA GEMM + CSR histogram (+ phis zero) ----------------
// Flat grid x = 128 hist blocks THEN 157*4 gemm blocks, 256 threads.
// Blocks dispatch in ascending x (performance assumption only; correctness is
// order-independent), so the 128 hist blocks start first and hide under the
// 628-block GEMM instead of costing their own dispatch + boundary. 32-bit LDS
// counters in the existing 52KB union -> no occupancy change (3 blocks/CU).
// Hist block 0 also zeroes phis, deleting the memset dispatch. 7 -> 5 dispatches.
#define LDK 136   // padded staging row (bf16): 272B stride, bank-balanced b128
struct GemmSmem {
    union {
        struct {
            unsigned short xs[64 * LDK];     // 17,408 B
            unsigned short wsh[128 * LDK];   // 34,816 B
        } in;
        float ot[64 * 132];                  // 33,792 B out-transpose tile
        int hist[N_NODES];                   // 40,000 B histogram
    };
};

__global__ __launch_bounds__(256) void gemm_hist(
    const float* __restrict__ x, const float* __restrict__ Wfc,
    const float* __restrict__ bfc, const float* __restrict__ Wres,
    float* __restrict__ resid, unsigned short* __restrict__ feat_b16,
    const float* __restrict__ wl, const float* __restrict__ wr,
    float* __restrict__ a_self, float* __restrict__ a_nb,
    const int4* __restrict__ edst4, int* __restrict__ bh,
    float* __restrict__ phis) {
    __shared__ GemmSmem sm;
    const int t = threadIdx.x;

    if (blockIdx.x < NB_CSR) {
        // ---- histogram path (blocks 0..127, dispatched first) ----
        const int blk = blockIdx.x;
        int* hist = sm.hist;
        if (blk == 0) {  // fold the old phis memset in here (pool runs much later)
            for (int i = t; i < N_GRAPHS * 2 * DIM; i += 256) phis[i] = 0.f;
        }
        for (int n = t; n < N_NODES; n += 256) hist[n] = 0;
        __syncthreads();
        const int base4 = blk * (EDGES_PER_BLK / 4);
        for (int i = t; i < EDGES_PER_BLK / 4; i += 256) {
            int4 d = edst4[base4 + i];
            atomicAdd(&hist[d.x], 1);
            atomicAdd(&hist[d.y], 1);
            atomicAdd(&hist[d.z], 1);
            atomicAdd(&hist[d.w], 1);
        }
        __syncthreads();
        int* dst = bh + (size_t)blk * N_NODES;
        for (int n = t; n < N_NODES; n += 256) dst[n] = hist[n];
        return;
    }

    // ---- GEMM path (verified R4/R8; math byte-identical) ----
    const int g = blockIdx.x - NB_CSR;
    const int y = g & 3;
    const int which = y & 1;
    const int b = y >> 1;
    const float* __restrict__ W = (which ? Wres : Wfc) + (size_t)b * DIM * DIM;
    const int n0 = (g >> 2) * 64;

    {   // stage x: 64 rows; thread t -> row t>>2, k-quarter (t&3)*32
        const int r = t >> 2;
        const int kq = (t & 3) * 32;
        const int n = n0 + r;
        unsigned short tmp[32];
        if (n < N_NODES) {
            const float4* px = reinterpret_cast<const float4*>(x + (size_t)n * DIM + kq);
#pragma unroll
            for (int i = 0; i < 8; ++i) {
                float4 v = px[i];
                tmp[4 * i]     = f2bf(v.x);
                tmp[4 * i + 1] = f2bf(v.y);
                tmp[4 * i + 2] = f2bf(v.z);
                tmp[4 * i + 3] = f2bf(v.w);
            }
        } else {
#pragma unroll
            for (int i = 0; i < 32; ++i) tmp[i] = 0;
        }
#pragma unroll
        for (int i = 0; i < 4; ++i)
            *reinterpret_cast<short8v*>(&sm.in.xs[r * LDK + kq + 8 * i]) =
                *reinterpret_cast<const short8v*>(&tmp[8 * i]);
    }
    {   // stage W: 128 rows; thread t -> row t>>1, k-half (t&1)*64
        const int r = t >> 1;
        const int kh = (t & 1) * 64;
        const float4* pw = reinterpret_cast<const float4*>(W + (size_t)r * DIM + kh);
        unsigned short tmp[64];
#pragma unroll
        for (int i = 0; i < 16; ++i) {
            float4 v = pw[i];
            tmp[4 * i]     = f2bf(v.x);
            tmp[4 * i + 1] = f2bf(v.y);
            tmp[4 * i + 2] = f2bf(v.z);
            tmp[4 * i + 3] = f2bf(v.w);
        }
#pragma unroll
        for (int i = 0; i < 8; ++i)
            *reinterpret_cast<short8v*>(&sm.in.wsh[r * LDK + kh + 8 * i]) =
                *reinterpret_cast<const short8v*>(&tmp[8 * i]);
    }
    __syncthreads();

    const int wave = t >> 6;
    const int lane = t & 63;
    const int l16 = lane & 15;
    const int l4 = lane >> 4;

    f32x4 acc[8];
#pragma unroll
    for (int nf = 0; nf < 8; ++nf) acc[nf] = (f32x4){0.f, 0.f, 0.f, 0.f};

    const int arow = wave * 16 + l16;
#pragma unroll
    for (int ks = 0; ks < 4; ++ks) {
        short8v af = *reinterpret_cast<const short8v*>(
            &sm.in.xs[arow * LDK + ks * 32 + l4 * 8]);
#pragma unroll
        for (int nf = 0; nf < 8; ++nf) {
            short8v bfr = *reinterpret_cast<const short8v*>(
                &sm.in.wsh[(nf * 16 + l16) * LDK + ks * 32 + l4 * 8]);
            acc[nf] = __builtin_amdgcn_mfma_f32_16x16x32_bf16(af, bfr, acc[nf], 0, 0, 0);
        }
    }

    __syncthreads();   // all MFMA LDS reads done; reuse LDS as fp32 out-tile
    const int lrow = wave * 16 + l4 * 4;   // local row base of this lane's 4 rows

    if (which == 0) {
        float wlv[8], wrv[8], bv[8];
#pragma unroll
        for (int nf = 0; nf < 8; ++nf) {
            wlv[nf] = wl[b * DIM + nf * 16 + l16];
            wrv[nf] = wr[b * DIM + nf * 16 + l16];
            bv[nf]  = bfc[b * DIM + nf * 16 + l16];
        }
#pragma unroll
        for (int r = 0; r < 4; ++r) {
            float ps = 0.f, pr = 0.f;
#pragma unroll
            for (int nf = 0; nf < 8; ++nf) {
                float f = acc[nf][r] + bv[nf];
                sm.ot[(lrow + r) * 132 + nf * 16 + l16] = f;
                ps += f * wlv[nf];
                pr += f * wrv[nf];
            }
            // reduce across the 16 cols-per-lane-group (l16 bits 0..3)
#pragma unroll
            for (int off = 1; off < 16; off <<= 1) {
                ps += __shfl_xor(ps, off, 64);
                pr += __shfl_xor(pr, off, 64);
            }
            int n = n0 + lrow + r;
            if (l16 == 0 && n < N_NODES) {
                a_self[b * N_NODES + n] = ps;
                a_nb[b * N_NODES + n] = pr;
            }
        }
    } else {
#pragma unroll
        for (int r = 0; r < 4; ++r)
#pragma unroll
            for (int nf = 0; nf < 8; ++nf)
                sm.ot[(lrow + r) * 132 + nf * 16 + l16] = acc[nf][r];
    }
    __syncthreads();

    // coalesced writeback: thread t -> row t>>2, col-quarter (t&3)*32
    const int rr = t >> 2;
    const int cq = (t & 3) * 32;
    const int n = n0 + rr;
    if (n < N_NODES) {
        if (which == 0) {
            unsigned short tmp[32];
#pragma unroll
            for (int i = 0; i < 8; ++i) {
                float4 v = *reinterpret_cast<const float4*>(&sm.ot[rr * 132 + cq + 4 * i]);
                tmp[4 * i]     = f2bf(v.x);
                tmp[4 * i + 1] = f2bf(v.y);
                tmp[4 * i + 2] = f2bf(v.z);
                tmp[4 * i + 3] = f2bf(v.w);
            }
            unsigned short* dst = feat_b16 + ((size_t)b * N_NODES + n) * DIM + cq;
#pragma unroll
            for (int i = 0; i < 4; ++i)
                *reinterpret_cast<short8v*>(dst + 8 * i) =
                    *reinterpret_cast<const short8v*>(&tmp[8 * i]);
        } else {
            float* dst = resid + ((size_t)b * N_NODES + n) * DIM + cq;
#pragma unroll
            for (int i = 0; i < 8; ++i)
                *reinterpret_cast<float4*>(dst + 4 * i) =
                    *reinterpret_cast<const float4*>(&sm.ot[rr * 132 + cq + 4 * i]);
        }
    }
}

// ---------------- softmax + weighted aggregation + residual + relu ----------------
// R10 version (best measured): 4-deep pipelined feat gather.
__device__ __forceinline__ void fma8(float acc[8], uint4 f, float w) {
#pragma unroll
    for (int k = 0; k < 4; ++k) {
        unsigned int u = (&f.x)[k];
        acc[2 * k]     += w * __uint_as_float(u << 16);
        acc[2 * k + 1] += w * __uint_as_float(u & 0xffff0000u);
    }
}

__global__ __launch_bounds__(256) void aggregate(
    const unsigned short* __restrict__ feat_b16, const float* __restrict__ resid,
    const float* __restrict__ a_self, const float* __restrict__ a_nb,
    const int* __restrict__ rowptr, const int* __restrict__ csr_src,
    float* __restrict__ out) {
    const int wave = threadIdx.x >> 6;
    const int lane = threadIdx.x & 63;
    const int n = blockIdx.x * 4 + wave;
    const int b = blockIdx.y;
    const int q = lane >> 4;     // edge slot within group of 4
    const int l16 = lane & 15;   // covers channels [l16*8, l16*8+8)
    const int start = rowptr[n];
    const int end = rowptr[n + 1];

    const float* __restrict__ anb = a_nb + b * N_NODES;
    const uint4* __restrict__ fb =
        reinterpret_cast<const uint4*>(feat_b16 + (size_t)b * N_NODES * DIM);
    const float asl = a_self[b * N_NODES + n];

    float acc[8];
#pragma unroll
    for (int k = 0; k < 8; ++k) acc[k] = 0.f;
    float dpart = 0.f;

    for (int c = start; c < end; c += 64) {
        int j = c + lane;
        float e = 0.f;
        int src = 0;
        if (j < end) {
            src = csr_src[j];
            float s = asl + anb[src];
            s = (s >= 0.f) ? s : NEG_SLOPE * s;
            e = __expf(s);
        }
        dpart += e;
        int cnt = end - c;
        if (cnt > 64) cnt = 64;
        const int iters = (cnt + 3) >> 2;    // groups of 4 edges, 1..16
        const int m4 = (iters + 3) >> 2;     // macro steps of 4 groups

#define GLOAD(F, W, IDX) { int _i = (IDX); W = __shfl(e, _i, 64);             \
        int _s = __shfl(src, _i, 64); F = fb[(size_t)_s * 16 + l16]; }

        float w0, w1, w2, w3;
        uint4 f0, f1, f2, f3;
        GLOAD(f0, w0, 0 + q);
        GLOAD(f1, w1, 4 + q);
        GLOAD(f2, w2, 8 + q);
        GLOAD(f3, w3, 12 + q);

        for (int m = 0; m < m4; ++m) {
            const bool more = (m + 1 < m4);          // wave-uniform
            const int nb16 = 16 * (m + 1);           // next macro-step lane base
            fma8(acc, f0, w0);
            if (more) GLOAD(f0, w0, nb16 + q);
            fma8(acc, f1, w1);
            if (more) GLOAD(f1, w1, nb16 + 4 + q);
            fma8(acc, f2, w2);
            if (more) GLOAD(f2, w2, nb16 + 8 + q);
            fma8(acc, f3, w3);
            if (more) GLOAD(f3, w3, nb16 + 12 + q);
        }
#undef GLOAD
    }

#pragma unroll
    for (int k = 0; k < 8; ++k) {
        acc[k] += __shfl_xor(acc[k], 16, 64);
        acc[k] += __shfl_xor(acc[k], 32, 64);
    }
    float denom = dpart;
#pragma unroll
    for (int off = 32; off > 0; off >>= 1) denom += __shfl_xor(denom, off, 64);

    if (q == 0) {
        float inv = (end > start) ? 1.f / denom : 0.f;
        const float4* rr = reinterpret_cast<const float4*>(
            resid + ((size_t)b * N_NODES + n) * DIM);
        float4 r0 = rr[l16 * 2];
        float4 r1 = rr[l16 * 2 + 1];
        float4 o0, o1;
        o0.x = fmaxf(acc[0] * inv + r0.x, 0.f);
        o0.y = fmaxf(acc[1] * inv + r0.y, 0.f);
        o0.z = fmaxf(acc[2] * inv + r0.z, 0.f);
        o0.w = fmaxf(acc[3] * inv + r0.w, 0.f);
        o1.x = fmaxf(acc[4] * inv + r1.x, 0.f);
        o1.y = fmaxf(acc[5] * inv + r1.y, 0.f);
        o1.z = fmaxf(acc[6] * inv + r1.z, 0.f);
        o1.w = fmaxf(acc[7] * inv + r1.w, 0.f);
        float4* po = reinterpret_cast<float4*>(out + (size_t)n * (2 * DIM) + b * DIM);
        po[l16 * 2] = o0;
        po[l16 * 2 + 1] = o1;
    }
}

// ---------------- per-graph sum pooling (chunked, 1024 blocks) ----------------
// R12 lesson: the 64-block chunkless variant measured 48us (latency-bound tiny
// grid). This chunked form (grid 64x16, bounded atomics) never entered top-5.
__device__ int lower_bound_dev(const int* __restrict__ a, int n, int key) {
    int lo = 0, hi = n;
    while (lo < hi) {
        int mid = (lo + hi) >> 1;
        if (a[mid] < key) lo = mid + 1;
        else hi = mid;
    }
    return lo;
}

__global__ __launch_bounds__(256) void pool_graphs(
    const float* __restrict__ h, const int* __restrict__ gids,
    float* __restrict__ phis) {
    const int g = blockIdx.x;
    const int chunk = blockIdx.y;
    const int tid = threadIdx.x;
    int lo = lower_bound_dev(gids, N_NODES, g);
    int hi = lower_bound_dev(gids, N_NODES, g + 1);
    float acc = 0.f;
    for (int n = lo + chunk; n < hi; n += 16) acc += h[(size_t)n * (2 * DIM) + tid];
    if (acc != 0.f) atomicAdd(&phis[(size_t)g * (2 * DIM) + tid], acc);
}

extern "C" void kernel_launch(void* const* d_in, const int* in_sizes, int n_in,
                              void* d_out, int out_size, void* d_ws, size_t ws_size,
                              hipStream_t stream) {
    const float* x    = (const float*)d_in[0];
    const int* esrc   = (const int*)d_in[1];
    const int* edst   = (const int*)d_in[2];
    const int* gids   = (const int*)d_in[3];
    const float* Wfc  = (const float*)d_in[4];
    const float* bfc  = (const float*)d_in[5];
    const float* wl   = (const float*)d_in[6];
    const float* wr   = (const float*)d_in[7];
    const float* Wres = (const float*)d_in[8];
    float* out = (float*)d_out;

    char* ws = (char*)d_ws;
    float* resid   = (float*)(ws + 10240000);
    float* a_self  = (float*)(ws + 20480000);
    float* a_nb    = (float*)(ws + 20560000);
    int*   deg     = (int*)(ws + 20640000);
    int*   rowptr  = (int*)(ws + 20688000);
    int*   csr_src = (int*)(ws + 20784000);
    unsigned short* feat_b16 = (unsigned short*)(ws + 23344000);
    int*   bh      = (int*)(ws + 28464000);

    float* phis = out + (size_t)N_NODES * 2 * DIM;

    // 5 dispatches: fused gemm+hist(+phis zero), node_scan, scatter(+rowptr),
    // aggregate, pool. No memsets, single stream.
    gemm_hist<<<NB_CSR + ((N_NODES + 63) / 64) * 4, 256, 0, stream>>>(
        x, Wfc, bfc, Wres, resid, feat_b16, wl, wr, a_self, a_nb,
        (const int4*)edst, bh, phis);

    csr_node_scan<<<(N_NODES + 255) / 256, 256, 0, stream>>>(bh, deg);
    csr_scatter<<<NB_CSR, 512, 0, stream>>>(
        (const int4*)esrc, (const int4*)edst, deg, bh, rowptr, csr_src);

    aggregate<<<dim3(2500, 2), 256, 0, stream>>>(
        feat_b16, resid, a_self, a_nb, rowptr, csr_src, out);
    pool_graphs<<<dim3(N_GRAPHS, 16), 256, 0, stream>>>(out, gids, phis);
}

// Round 15
// 156.163 us; speedup vs baseline: 1.2700x; 1.0086x over previous
//
#include <hip/hip_runtime.h>
#include <hip/hip_bf16.h>
#include <math.h>

#define N_NODES 10000
#define N_EDGES 640000
#define N_GRAPHS 64
#define DIM 128
#define NEG_SLOPE 0.01f
#define NB_CSR 128            // histogram partitions (5000 edges each)
#define EDGES_PER_BLK (N_EDGES / NB_CSR)

// ---------------- workspace layout (bytes) ----------------
// (fp32 feat slot at 0 unused; layout kept stable)
// resid    : 10,240,000 .. 20,480,000   float[2][10000][128]
// a_self   : 20,480,000                 float[2][10000]
// a_nb     : 20,560,000                 float[2][10000]
// deg      : 20,640,000                 int[10000]
// rowptr   : 20,688,000                 int[10001]
// csr_src  : 20,784,000                 int[640000]
// feat_b16 : 23,344,000 .. 28,464,000   bf16[2][10000][128]
// bh       : 28,464,000 .. 33,584,000   int[128][10000]
//
// LEDGER (measured A/B facts, rounds 0-14):
//  - fork-join side stream: +26us (R9 pure launcher A/B). Single stream only.
//  - LDS-staged node_scan: +32.5us (R6-R7). Keep dependent-chain version.
//  - MFMA gemm + LDS-transpose epilogue + fused attn scalars: -7.5us (R8).
//  - global returning atomics for CSR: +60us (R1). Keep LDS-cursor scatter.
//  - pool fusion into aggregate via phis atomics: +65us (R5). Keep separate.
//  - 4-deep feat-gather pipeline in aggregate: null (R10).
//  - b-merged aggregate: null (R11).
//  - scan_deg fused into scatter prologue: ~neutral, 1 fewer dispatch (R12/R13).
//  - 64-block chunkless pool: +43us (R12). Tiny grids = latency death.
//  - hist fused into gemm as flat-x-first blocks + 32b counters: -2..-4us (R14).
//    (R2's +30us was grid-z serial tail + packed counters.)
//  - R15 test: XCD-parity swizzle of aggregate grid so each XCD's L2 holds
//    only one b's feat_b16 (2.56MB < 4MB L2; combined 5.12MB thrashes).

__device__ __forceinline__ unsigned short f2bf(float f) {
    __hip_bfloat16 h = __float2bfloat16(f);
    return *reinterpret_cast<unsigned short*>(&h);
}

typedef __attribute__((ext_vector_type(8))) short short8v;  // 8 bf16 in 4 VGPR
typedef __attribute__((ext_vector_type(4))) float f32x4;

// ---------------- CSR build: per-node scan over partitions ----------------
// Constant-stride offsets -> LLVM proves independence, pipelines the loads.
// (LDS-staged variant measured +32.5us worse, R6-R7.)
__global__ __launch_bounds__(256) void csr_node_scan(int* __restrict__ bh,
                                                     int* __restrict__ deg) {
    int n = blockIdx.x * 256 + threadIdx.x;
    if (n >= N_NODES) return;
    int running = 0;
    for (int blk = 0; blk < NB_CSR; ++blk) {
        int* p = bh + (size_t)blk * N_NODES + n;
        int v = *p;
        *p = running;
        running += v;
    }
    deg[n] = running;
}

// ---------------- CSR build: scatter (rowptr scan fused in prologue) ---
__global__ __launch_bounds__(512) void csr_scatter(
    const int4* __restrict__ esrc4, const int4* __restrict__ edst4,
    const int* __restrict__ deg, const int* __restrict__ bh,
    int* __restrict__ rowptr, int* __restrict__ csr_src) {
    __shared__ int cur[N_NODES];        // 40,000 B
    __shared__ int psum[512];
    const int blk = blockIdx.x;
    const int t = threadIdx.x;

    // strip sums: thread t owns nodes [t*20, t*20+20)
    const int base = t * 20;
    int cnt = N_NODES - base;
    if (cnt < 0) cnt = 0;
    if (cnt > 20) cnt = 20;
    int s = 0;
    for (int i = 0; i < cnt; ++i) s += deg[base + i];
    psum[t] = s;
    __syncthreads();
    for (int off = 1; off < 512; off <<= 1) {
        int v = 0;
        if (t >= off) v = psum[t - off];
        __syncthreads();
        if (t >= off) psum[t] += v;
        __syncthreads();
    }
    int run = (t == 0) ? 0 : psum[t - 1];   // exclusive prefix of strip
    for (int i = 0; i < cnt; ++i) {
        cur[base + i] = run;
        if (blk == 0) rowptr[base + i] = run;
        run += deg[base + i];
    }
    if (blk == 0 && t == 0) rowptr[N_NODES] = psum[511];
    __syncthreads();

    // add per-partition offsets (coalesced)
    const int* boff = bh + (size_t)blk * N_NODES;
    for (int n = t; n < N_NODES; n += 512) cur[n] += boff[n];
    __syncthreads();

    const int base4 = blk * (EDGES_PER_BLK / 4);
    for (int i = t; i < EDGES_PER_BLK / 4; i += 512) {
        int4 sv = esrc4[base4 + i];
        int4 d = edst4[base4 + i];
        csr_src[atomicAdd(&cur[d.x], 1)] = sv.x;
        csr_src[atomicAdd(&cur[d.y], 1)] = sv.y;
        csr_src[atomicAdd(&cur[d.z], 1)] = sv.z;
        csr_src[atomicAdd(&cur[d.w], 1)] = sv.w;
    }
}

// ---------------- fused MFMA GEMM + CSR histogram (+ phis zero) ----------------
// Flat grid x = 128 hist blocks THEN 157*4 gemm blocks, 256 threads (R14, -2us).
#define LDK 136   // padded staging row (bf16): 272B stride, bank-balanced b128
struct GemmSmem {
    union {
        struct {
            unsigned short xs[64 * LDK];     // 17,408 B
            unsigned short wsh[128 * LDK];   // 34,816 B
        } in;
        float ot[64 * 132];                  // 33,792 B out-transpose tile
        int hist[N_NODES];                   // 40,000 B histogram
    };
};

__global__ __launch_bounds__(256) void gemm_hist(
    const float* __restrict__ x, const float* __restrict__ Wfc,
    const float* __restrict__ bfc, const float* __restrict__ Wres,
    float* __restrict__ resid, unsigned short* __restrict__ feat_b16,
    const float* __restrict__ wl, const float* __restrict__ wr,
    float* __restrict__ a_self, float* __restrict__ a_nb,
    const int4* __restrict__ edst4, int* __restrict__ bh,
    float* __restrict__ phis) {
    __shared__ GemmSmem sm;
    const int t = threadIdx.x;

    if (blockIdx.x < NB_CSR) {
        // ---- histogram path (blocks 0..127, dispatched first) ----
        const int blk = blockIdx.x;
        int* hist = sm.hist;
        if (blk == 0) {  // fold the old phis memset in here (pool runs much later)
            for (int i = t; i < N_GRAPHS * 2 * DIM; i += 256) phis[i] = 0.f;
        }
        for (int n = t; n < N_NODES; n += 256) hist[n] = 0;
        __syncthreads();
        const int base4 = blk * (EDGES_PER_BLK / 4);
        for (int i = t; i < EDGES_PER_BLK / 4; i += 256) {
            int4 d = edst4[base4 + i];
            atomicAdd(&hist[d.x], 1);
            atomicAdd(&hist[d.y], 1);
            atomicAdd(&hist[d.z], 1);
            atomicAdd(&hist[d.w], 1);
        }
        __syncthreads();
        int* dst = bh + (size_t)blk * N_NODES;
        for (int n = t; n < N_NODES; n += 256) dst[n] = hist[n];
        return;
    }

    // ---- GEMM path (verified R4/R8; math byte-identical) ----
    const int g = blockIdx.x - NB_CSR;
    const int y = g & 3;
    const int which = y & 1;
    const int b = y >> 1;
    const float* __restrict__ W = (which ? Wres : Wfc) + (size_t)b * DIM * DIM;
    const int n0 = (g >> 2) * 64;

    {   // stage x: 64 rows; thread t -> row t>>2, k-quarter (t&3)*32
        const int r = t >> 2;
        const int kq = (t & 3) * 32;
        const int n = n0 + r;
        unsigned short tmp[32];
        if (n < N_NODES) {
            const float4* px = reinterpret_cast<const float4*>(x + (size_t)n * DIM + kq);
#pragma unroll
            for (int i = 0; i < 8; ++i) {
                float4 v = px[i];
                tmp[4 * i]     = f2bf(v.x);
                tmp[4 * i + 1] = f2bf(v.y);
                tmp[4 * i + 2] = f2bf(v.z);
                tmp[4 * i + 3] = f2bf(v.w);
            }
        } else {
#pragma unroll
            for (int i = 0; i < 32; ++i) tmp[i] = 0;
        }
#pragma unroll
        for (int i = 0; i < 4; ++i)
            *reinterpret_cast<short8v*>(&sm.in.xs[r * LDK + kq + 8 * i]) =
                *reinterpret_cast<const short8v*>(&tmp[8 * i]);
    }
    {   // stage W: 128 rows; thread t -> row t>>1, k-half (t&1)*64
        const int r = t >> 1;
        const int kh = (t & 1) * 64;
        const float4* pw = reinterpret_cast<const float4*>(W + (size_t)r * DIM + kh);
        unsigned short tmp[64];
#pragma unroll
        for (int i = 0; i < 16; ++i) {
            float4 v = pw[i];
            tmp[4 * i]     = f2bf(v.x);
            tmp[4 * i + 1] = f2bf(v.y);
            tmp[4 * i + 2] = f2bf(v.z);
            tmp[4 * i + 3] = f2bf(v.w);
        }
#pragma unroll
        for (int i = 0; i < 8; ++i)
            *reinterpret_cast<short8v*>(&sm.in.wsh[r * LDK + kh + 8 * i]) =
                *reinterpret_cast<const short8v*>(&tmp[8 * i]);
    }
    __syncthreads();

    const int wave = t >> 6;
    const int lane = t & 63;
    const int l16 = lane & 15;
    const int l4 = lane >> 4;

    f32x4 acc[8];
#pragma unroll
    for (int nf = 0; nf < 8; ++nf) acc[nf] = (f32x4){0.f, 0.f, 0.f, 0.f};

    const int arow = wave * 16 + l16;
#pragma unroll
    for (int ks = 0; ks < 4; ++ks) {
        short8v af = *reinterpret_cast<const short8v*>(
            &sm.in.xs[arow * LDK + ks * 32 + l4 * 8]);
#pragma unroll
        for (int nf = 0; nf < 8; ++nf) {
            short8v bfr = *reinterpret_cast<const short8v*>(
                &sm.in.wsh[(nf * 16 + l16) * LDK + ks * 32 + l4 * 8]);
            acc[nf] = __builtin_amdgcn_mfma_f32_16x16x32_bf16(af, bfr, acc[nf], 0, 0, 0);
        }
    }

    __syncthreads();   // all MFMA LDS reads done; reuse LDS as fp32 out-tile
    const int lrow = wave * 16 + l4 * 4;   // local row base of this lane's 4 rows

    if (which == 0) {
        float wlv[8], wrv[8], bv[8];
#pragma unroll
        for (int nf = 0; nf < 8; ++nf) {
            wlv[nf] = wl[b * DIM + nf * 16 + l16];
            wrv[nf] = wr[b * DIM + nf * 16 + l16];
            bv[nf]  = bfc[b * DIM + nf * 16 + l16];
        }
#pragma unroll
        for (int r = 0; r < 4; ++r) {
            float ps = 0.f, pr = 0.f;
#pragma unroll
            for (int nf = 0; nf < 8; ++nf) {
                float f = acc[nf][r] + bv[nf];
                sm.ot[(lrow + r) * 132 + nf * 16 + l16] = f;
                ps += f * wlv[nf];
                pr += f * wrv[nf];
            }
            // reduce across the 16 cols-per-lane-group (l16 bits 0..3)
#pragma unroll
            for (int off = 1; off < 16; off <<= 1) {
                ps += __shfl_xor(ps, off, 64);
                pr += __shfl_xor(pr, off, 64);
            }
            int n = n0 + lrow + r;
            if (l16 == 0 && n < N_NODES) {
                a_self[b * N_NODES + n] = ps;
                a_nb[b * N_NODES + n] = pr;
            }
        }
    } else {
#pragma unroll
        for (int r = 0; r < 4; ++r)
#pragma unroll
            for (int nf = 0; nf < 8; ++nf)
                sm.ot[(lrow + r) * 132 + nf * 16 + l16] = acc[nf][r];
    }
    __syncthreads();

    // coalesced writeback: thread t -> row t>>2, col-quarter (t&3)*32
    const int rr = t >> 2;
    const int cq = (t & 3) * 32;
    const int n = n0 + rr;
    if (n < N_NODES) {
        if (which == 0) {
            unsigned short tmp[32];
#pragma unroll
            for (int i = 0; i < 8; ++i) {
                float4 v = *reinterpret_cast<const float4*>(&sm.ot[rr * 132 + cq + 4 * i]);
                tmp[4 * i]     = f2bf(v.x);
                tmp[4 * i + 1] = f2bf(v.y);
                tmp[4 * i + 2] = f2bf(v.z);
                tmp[4 * i + 3] = f2bf(v.w);
            }
            unsigned short* dst = feat_b16 + ((size_t)b * N_NODES + n) * DIM + cq;
#pragma unroll
            for (int i = 0; i < 4; ++i)
                *reinterpret_cast<short8v*>(dst + 8 * i) =
                    *reinterpret_cast<const short8v*>(&tmp[8 * i]);
        } else {
            float* dst = resid + ((size_t)b * N_NODES + n) * DIM + cq;
#pragma unroll
            for (int i = 0; i < 8; ++i)
                *reinterpret_cast<float4*>(dst + 4 * i) =
                    *reinterpret_cast<const float4*>(&sm.ot[rr * 132 + cq + 4 * i]);
        }
    }
}

// ---------------- softmax + weighted aggregation + residual + relu ----------------
// R15 change: grid (5000) flat, b = blockIdx.x & 1, node chunk = blockIdx.x >> 1.
// XCD assignment round-robins on blockIdx (performance-only assumption): even
// blocks (b=0) land on even XCDs, odd (b=1) on odd XCDs. Each XCD's L2 then
// caches only ONE b's feat_b16 (2.56MB < 4MB) instead of both (5.12MB thrash).
// Body otherwise byte-identical to R10/R14.
__device__ __forceinline__ void fma8(float acc[8], uint4 f, float w) {
#pragma unroll
    for (int k = 0; k < 4; ++k) {
        unsigned int u = (&f.x)[k];
        acc[2 * k]     += w * __uint_as_float(u << 16);
        acc[2 * k + 1] += w * __uint_as_float(u & 0xffff0000u);
    }
}

__global__ __launch_bounds__(256) void aggregate(
    const unsigned short* __restrict__ feat_b16, const float* __restrict__ resid,
    const float* __restrict__ a_self, const float* __restrict__ a_nb,
    const int* __restrict__ rowptr, const int* __restrict__ csr_src,
    float* __restrict__ out) {
    const int wave = threadIdx.x >> 6;
    const int lane = threadIdx.x & 63;
    const int b = blockIdx.x & 1;               // XCD-parity: b tied to block parity
    const int n = (blockIdx.x >> 1) * 4 + wave;
    const int q = lane >> 4;     // edge slot within group of 4
    const int l16 = lane & 15;   // covers channels [l16*8, l16*8+8)
    const int start = rowptr[n];
    const int end = rowptr[n + 1];

    const float* __restrict__ anb = a_nb + b * N_NODES;
    const uint4* __restrict__ fb =
        reinterpret_cast<const uint4*>(feat_b16 + (size_t)b * N_NODES * DIM);
    const float asl = a_self[b * N_NODES + n];

    float acc[8];
#pragma unroll
    for (int k = 0; k < 8; ++k) acc[k] = 0.f;
    float dpart = 0.f;

    for (int c = start; c < end; c += 64) {
        int j = c + lane;
        float e = 0.f;
        int src = 0;
        if (j < end) {
            src = csr_src[j];
            float s = asl + anb[src];
            s = (s >= 0.f) ? s : NEG_SLOPE * s;
            e = __expf(s);
        }
        dpart += e;
        int cnt = end - c;
        if (cnt > 64) cnt = 64;
        const int iters = (cnt + 3) >> 2;    // groups of 4 edges, 1..16
        const int m4 = (iters + 3) >> 2;     // macro steps of 4 groups

#define GLOAD(F, W, IDX) { int _i = (IDX); W = __shfl(e, _i, 64);             \
        int _s = __shfl(src, _i, 64); F = fb[(size_t)_s * 16 + l16]; }

        float w0, w1, w2, w3;
        uint4 f0, f1, f2, f3;
        GLOAD(f0, w0, 0 + q);
        GLOAD(f1, w1, 4 + q);
        GLOAD(f2, w2, 8 + q);
        GLOAD(f3, w3, 12 + q);

        for (int m = 0; m < m4; ++m) {
            const bool more = (m + 1 < m4);          // wave-uniform
            const int nb16 = 16 * (m + 1);           // next macro-step lane base
            fma8(acc, f0, w0);
            if (more) GLOAD(f0, w0, nb16 + q);
            fma8(acc, f1, w1);
            if (more) GLOAD(f1, w1, nb16 + 4 + q);
            fma8(acc, f2, w2);
            if (more) GLOAD(f2, w2, nb16 + 8 + q);
            fma8(acc, f3, w3);
            if (more) GLOAD(f3, w3, nb16 + 12 + q);
        }
#undef GLOAD
    }

#pragma unroll
    for (int k = 0; k < 8; ++k) {
        acc[k] += __shfl_xor(acc[k], 16, 64);
        acc[k] += __shfl_xor(acc[k], 32, 64);
    }
    float denom = dpart;
#pragma unroll
    for (int off = 32; off > 0; off >>= 1) denom += __shfl_xor(denom, off, 64);

    if (q == 0) {
        float inv = (end > start) ? 1.f / denom : 0.f;
        const float4* rr = reinterpret_cast<const float4*>(
            resid + ((size_t)b * N_NODES + n) * DIM);
        float4 r0 = rr[l16 * 2];
        float4 r1 = rr[l16 * 2 + 1];
        float4 o0, o1;
        o0.x = fmaxf(acc[0] * inv + r0.x, 0.f);
        o0.y = fmaxf(acc[1] * inv + r0.y, 0.f);
        o0.z = fmaxf(acc[2] * inv + r0.z, 0.f);
        o0.w = fmaxf(acc[3] * inv + r0.w, 0.f);
        o1.x = fmaxf(acc[4] * inv + r1.x, 0.f);
        o1.y = fmaxf(acc[5] * inv + r1.y, 0.f);
        o1.z = fmaxf(acc[6] * inv + r1.z, 0.f);
        o1.w = fmaxf(acc[7] * inv + r1.w, 0.f);
        float4* po = reinterpret_cast<float4*>(out + (size_t)n * (2 * DIM) + b * DIM);
        po[l16 * 2] = o0;
        po[l16 * 2 + 1] = o1;
    }
}

// ---------------- per-graph sum pooling (chunked, 1024 blocks) ----------------
__device__ int lower_bound_dev(const int* __restrict__ a, int n, int key) {
    int lo = 0, hi = n;
    while (lo < hi) {
        int mid = (lo + hi) >> 1;
        if (a[mid] < key) lo = mid + 1;
        else hi = mid;
    }
    return lo;
}

__global__ __launch_bounds__(256) void pool_graphs(
    const float* __restrict__ h, const int* __restrict__ gids,
    float* __restrict__ phis) {
    const int g = blockIdx.x;
    const int chunk = blockIdx.y;
    const int tid = threadIdx.x;
    int lo = lower_bound_dev(gids, N_NODES, g);
    int hi = lower_bound_dev(gids, N_NODES, g + 1);
    float acc = 0.f;
    for (int n = lo + chunk; n < hi; n += 16) acc += h[(size_t)n * (2 * DIM) + tid];
    if (acc != 0.f) atomicAdd(&phis[(size_t)g * (2 * DIM) + tid], acc);
}

extern "C" void kernel_launch(void* const* d_in, const int* in_sizes, int n_in,
                              void* d_out, int out_size, void* d_ws, size_t ws_size,
                              hipStream_t stream) {
    const float* x    = (const float*)d_in[0];
    const int* esrc   = (const int*)d_in[1];
    const int* edst   = (const int*)d_in[2];
    const int* gids   = (const int*)d_in[3];
    const float* Wfc  = (const float*)d_in[4];
    const float* bfc  = (const float*)d_in[5];
    const float* wl   = (const float*)d_in[6];
    const float* wr   = (const float*)d_in[7];
    const float* Wres = (const float*)d_in[8];
    float* out = (float*)d_out;

    char* ws = (char*)d_ws;
    float* resid   = (float*)(ws + 10240000);
    float* a_self  = (float*)(ws + 20480000);
    float* a_nb    = (float*)(ws + 20560000);
    int*   deg     = (int*)(ws + 20640000);
    int*   rowptr  = (int*)(ws + 20688000);
    int*   csr_src = (int*)(ws + 20784000);
    unsigned short* feat_b16 = (unsigned short*)(ws + 23344000);
    int*   bh      = (int*)(ws + 28464000);

    float* phis = out + (size_t)N_NODES * 2 * DIM;

    // 5 dispatches: fused gemm+hist(+phis zero), node_scan, scatter(+rowptr),
    // aggregate, pool. No memsets, single stream.
    gemm_hist<<<NB_CSR + ((N_NODES + 63) / 64) * 4, 256, 0, stream>>>(
        x, Wfc, bfc, Wres, resid, feat_b16, wl, wr, a_self, a_nb,
        (const int4*)edst, bh, phis);

    csr_node_scan<<<(N_NODES + 255) / 256, 256, 0, stream>>>(bh, deg);
    csr_scatter<<<NB_CSR, 512, 0, stream>>>(
        (const int4*)esrc, (const int4*)edst, deg, bh, rowptr, csr_src);

    aggregate<<<5000, 256, 0, stream>>>(
        feat_b16, resid, a_self, a_nb, rowptr, csr_src, out);
    pool_graphs<<<dim3(N_GRAPHS, 16), 256, 0, stream>>>(out, gids, phis);
}